// Round 6
// baseline (212.859 us; speedup 1.0000x reference)
//
#include <hip/hip_runtime.h>

#define NNODE  50000
#define NHEDGE 10000
#define NEDGE  300000
#define HD     256
#define NS     (NHEDGE + NNODE)   // 60000 combined segments
#define SCAN_B 59                 // ceil(NS/1024)
#define CVT_B  ((NNODE * HD) / (256 * 8))   // 6250
#define HIST_B ((NEDGE + 255) / 256)        // 1172

typedef __attribute__((ext_vector_type(8))) short bf16x8;
typedef __attribute__((ext_vector_type(8))) unsigned short u16x8;
typedef __attribute__((ext_vector_type(4))) float f32x4;

__device__ __forceinline__ float prelu(float v, float a){ return v > 0.f ? v : a*v; }
__device__ __forceinline__ unsigned short f2bf(float f){
  unsigned u = __float_as_uint(f);
  return (unsigned short)((u + 0x7FFFu + ((u>>16)&1u)) >> 16);   // RNE
}
__device__ __forceinline__ float bf2f(unsigned short h){
  return __uint_as_float(((unsigned)h) << 16);
}

// ---------------------------------------------------------------------------
// Weight prep, one block per output row o:
//   Wb0[o][i] = bf16( sum_h W_n2e[o][h]*W_in[h][i] )   (B for GEMM0, [n][k])
//   Wb1[o][i] = bf16( W_e2n[o][i] )                    (B for GEMM1, [n][k])
//   bc[o]     = dot(W_n2e[o,:], b_in) + b_n2e[o]       (LDS reduce)
//   also zeroes cnts[] and pos[] (65536 threads >= NS each)
// ---------------------------------------------------------------------------
__global__ __launch_bounds__(256) void k_wprep(
    const float* __restrict__ W_in, const float* __restrict__ b_in,
    const float* __restrict__ W_n2e, const float* __restrict__ b_n2e,
    const float* __restrict__ W_e2n,
    unsigned short* __restrict__ Wb0, unsigned short* __restrict__ Wb1,
    float* __restrict__ bc, int* __restrict__ cnts, int* __restrict__ pos){
  int o = blockIdx.x, t = threadIdx.x;
  int zi = o*256 + t;
  if(zi < NS){ cnts[zi] = 0; pos[zi] = 0; }
  __shared__ float wn[HD];
  __shared__ float red[4];
  wn[t] = W_n2e[(size_t)o*HD + t];
  __syncthreads();
  float pb = wn[t] * b_in[t];
  #pragma unroll
  for(int d = 32; d > 0; d >>= 1) pb += __shfl_down(pb, d);
  if((t & 63) == 0) red[t >> 6] = pb;
  float acc = 0.f;
  #pragma unroll 8
  for(int h = 0; h < HD; ++h) acc += wn[h] * W_in[(size_t)h*HD + t];
  Wb0[(size_t)o*HD + t] = f2bf(acc);
  Wb1[(size_t)o*HD + t] = f2bf(W_e2n[(size_t)o*HD + t]);
  __syncthreads();
  if(t == 0) bc[o] = red[0] + red[1] + red[2] + red[3] + b_n2e[o];
}

// ---------------------------------------------------------------------------
// Merged: [0, CVT_B) blocks convert n_feat -> pre-scaled bf16 table
//         [CVT_B, CVT_B+HIST_B) blocks do the combined segment histogram
// (independent work; cnts pre-zeroed by k_wprep)
// ---------------------------------------------------------------------------
__global__ __launch_bounds__(256) void k_cvthist(
    const float* __restrict__ n_feat, const float* __restrict__ nrw,
    const int* __restrict__ node_idx, const int* __restrict__ hedge_idx,
    unsigned short* __restrict__ tabw, int* __restrict__ cnts){
  int blk = blockIdx.x, t = threadIdx.x;
  if(blk < CVT_B){
    size_t i8 = (size_t)blk*256 + t;
    int row = (int)(i8 >> 5);            // 32 x u16x8 per 256-col row
    float w = nrw[row];
    const float4* f4 = (const float4*)n_feat;
    float4 a = f4[i8*2], c = f4[i8*2 + 1];
    u16x8 o;
    o[0] = f2bf(w*a.x); o[1] = f2bf(w*a.y); o[2] = f2bf(w*a.z); o[3] = f2bf(w*a.w);
    o[4] = f2bf(w*c.x); o[5] = f2bf(w*c.y); o[6] = f2bf(w*c.z); o[7] = f2bf(w*c.w);
    ((u16x8*)tabw)[i8] = o;
  } else {
    int e = (blk - CVT_B)*256 + t;
    if(e < NEDGE){
      atomicAdd(&cnts[hedge_idx[e]], 1);
      atomicAdd(&cnts[NHEDGE + node_idx[e]], 1);
    }
  }
}

// ---------------------------------------------------------------------------
// Scan step A: per-1024-chunk block sums
// ---------------------------------------------------------------------------
__global__ __launch_bounds__(256) void k_scanA(const int* __restrict__ cnts, int* __restrict__ bsum){
  int idx4 = blockIdx.x*256 + threadIdx.x;
  int4 v = make_int4(0,0,0,0);
  if(idx4 < NS/4) v = ((const int4*)cnts)[idx4];
  int s = v.x + v.y + v.z + v.w;
  __shared__ int red[256];
  red[threadIdx.x] = s; __syncthreads();
  for(int d = 128; d > 0; d >>= 1){
    if(threadIdx.x < d) red[threadIdx.x] += red[threadIdx.x + d];
    __syncthreads();
  }
  if(threadIdx.x == 0) bsum[blockIdx.x] = red[0];
}

// ---------------------------------------------------------------------------
// Scan step C (scanB inlined): wave 0 reduces bsum[0:blockIdx) for the block
// prefix, then the block emits its 1024 exclusive offsets.
// ---------------------------------------------------------------------------
__global__ __launch_bounds__(256) void k_scanC(const int* __restrict__ cnts,
        const int* __restrict__ bsum, int* __restrict__ offs){
  __shared__ int base_s;
  __shared__ int sc[256];
  int t = threadIdx.x;
  if(t < 64){
    int v = (t < (int)blockIdx.x) ? bsum[t] : 0;   // blockIdx.x <= 58 < 64
    #pragma unroll
    for(int d = 32; d > 0; d >>= 1) v += __shfl_down(v, d);
    if(t == 0) base_s = v;
  }
  int idx4 = blockIdx.x*256 + t;
  int4 v4 = make_int4(0,0,0,0);
  if(idx4 < NS/4) v4 = ((const int4*)cnts)[idx4];
  int s = v4.x + v4.y + v4.z + v4.w;
  sc[t] = s; __syncthreads();
  for(int d = 1; d < 256; d <<= 1){
    int q = (t >= d) ? sc[t-d] : 0; __syncthreads();
    sc[t] += q; __syncthreads();
  }
  int excl = sc[t] - s + base_s;
  int base = idx4*4;
  if(base < NS){
    int r = excl;
    offs[base]   = r; r += v4.x;
    offs[base+1] = r; r += v4.y;
    offs[base+2] = r; r += v4.z;
    offs[base+3] = r;
  }
  if(blockIdx.x == 0 && t == 0) offs[NS] = 2*NEDGE;   // total is a known constant
}

// ---------------------------------------------------------------------------
// Fill CSR buckets (hedge buckets in csrc[0..NEDGE), node buckets after).
// ---------------------------------------------------------------------------
__global__ void k_fill(const int* __restrict__ node_idx, const int* __restrict__ hedge_idx,
                       const int* __restrict__ offs, int* __restrict__ pos,
                       int* __restrict__ csrc){
  int e = blockIdx.x*256 + threadIdx.x;
  if(e < NEDGE){
    int j = hedge_idx[e];
    int n = node_idx[e];
    int p = offs[j] + atomicAdd(&pos[j], 1);
    csrc[p] = n;
    int q = offs[NHEDGE + n] + atomicAdd(&pos[NHEDGE + n], 1);
    csrc[q] = j;
  }
}

// ---------------------------------------------------------------------------
// Phase-1 aggregation: 2 hedges per wave (32 lanes each), 16B/lane (u16x8),
// depth-4 prefetch -> 2x bytes in flight vs 8B/lane.
// ---------------------------------------------------------------------------
__global__ __launch_bounds__(256) void k_agg1(const unsigned short* __restrict__ tabw,
        const float* __restrict__ nrw,
        const int* __restrict__ offs, const int* __restrict__ csrc,
        unsigned short* __restrict__ aggx_b, float* __restrict__ aggw){
  int wv = threadIdx.x >> 6, lane = threadIdx.x & 63;
  int sub = lane >> 5, sl = lane & 31;
  int j = blockIdx.x*8 + wv*2 + sub;
  int b = offs[j], cnt = offs[j+1] - b;
  const u16x8* tab = (const u16x8*)tabw;   // 32 x u16x8 per row
  float acc[8] = {0.f,0.f,0.f,0.f,0.f,0.f,0.f,0.f};
  float sw = 0.f;
  u16x8 z8 = {0,0,0,0,0,0,0,0};
  u16x8 v0=z8, v1=z8, v2=z8, v3=z8;
  float w0=0.f, w1=0.f, w2=0.f, w3=0.f;
  if(cnt > 0){ int n = csrc[b];   w0 = nrw[n]; v0 = tab[(size_t)n*32 + sl]; }
  if(cnt > 1){ int n = csrc[b+1]; w1 = nrw[n]; v1 = tab[(size_t)n*32 + sl]; }
  if(cnt > 2){ int n = csrc[b+2]; w2 = nrw[n]; v2 = tab[(size_t)n*32 + sl]; }
  if(cnt > 3){ int n = csrc[b+3]; w3 = nrw[n]; v3 = tab[(size_t)n*32 + sl]; }
  int k = 0;
  while(k < cnt){
    { u16x8 cv = v0; float cw = w0;
      if(k + 4 < cnt){ int n = csrc[b+k+4]; w0 = nrw[n]; v0 = tab[(size_t)n*32 + sl]; }
      #pragma unroll
      for(int c = 0; c < 8; ++c) acc[c] += bf2f(cv[c]);
      sw += cw; }
    if(++k >= cnt) break;
    { u16x8 cv = v1; float cw = w1;
      if(k + 4 < cnt){ int n = csrc[b+k+4]; w1 = nrw[n]; v1 = tab[(size_t)n*32 + sl]; }
      #pragma unroll
      for(int c = 0; c < 8; ++c) acc[c] += bf2f(cv[c]);
      sw += cw; }
    if(++k >= cnt) break;
    { u16x8 cv = v2; float cw = w2;
      if(k + 4 < cnt){ int n = csrc[b+k+4]; w2 = nrw[n]; v2 = tab[(size_t)n*32 + sl]; }
      #pragma unroll
      for(int c = 0; c < 8; ++c) acc[c] += bf2f(cv[c]);
      sw += cw; }
    if(++k >= cnt) break;
    { u16x8 cv = v3; float cw = w3;
      if(k + 4 < cnt){ int n = csrc[b+k+4]; w3 = nrw[n]; v3 = tab[(size_t)n*32 + sl]; }
      #pragma unroll
      for(int c = 0; c < 8; ++c) acc[c] += bf2f(cv[c]);
      sw += cw; }
    ++k;
  }
  u16x8 ob;
  #pragma unroll
  for(int c = 0; c < 8; ++c) ob[c] = f2bf(acc[c]);
  ((u16x8*)aggx_b)[(size_t)j*32 + sl] = ob;
  if(sl == 0) aggw[j] = sw;
}

// ---------------------------------------------------------------------------
// Fused GEMM0+GEMM1. Block owns 128 rows (4 waves x 32 rows).
// Phase A: efeat = prelu((aggx@Wc^T + aggw*bc)/hrs) -> out_ef (f32) + ef_b (bf16)
// Phase B: y = hrw*(efeat@W_e2n^T + be)             -> y_b (bf16)
// Phase B reads ONLY this block's rows of ef_b (written in phase A;
// __syncthreads drains stores). y_b aliases aggx_b: each block writes exactly
// the rows it finished reading in phase A -> no cross-block hazard.
// ---------------------------------------------------------------------------
__global__ __launch_bounds__(256) void k_gemm01(
    const unsigned short* __restrict__ xb, const unsigned short* __restrict__ Wb0,
    const unsigned short* __restrict__ Wb1,
    const float* __restrict__ aggw, const float* __restrict__ hrs,
    const float* __restrict__ hrw, const float* __restrict__ bc,
    const float* __restrict__ be, const float* __restrict__ alpha_p,
    float* __restrict__ out_ef, unsigned short* __restrict__ ef_b,
    unsigned short* __restrict__ y_b){
  int wv = threadIdx.x >> 6, lane = threadIdx.x & 63;
  int m0 = blockIdx.x*128 + wv*32;
  int lr = lane & 15, lk = (lane >> 4) << 3, rb = (lane >> 4) << 2;
  float alpha = *alpha_p;
  const bf16x8 zero8 = {0,0,0,0,0,0,0,0};
  // ---- phase A ----
  for(int n0 = 0; n0 < HD; n0 += 64){
    f32x4 acc[2][4];
    #pragma unroll
    for(int a = 0; a < 2; ++a)
      #pragma unroll
      for(int b = 0; b < 4; ++b) acc[a][b] = (f32x4){0.f,0.f,0.f,0.f};
    #pragma unroll
    for(int kc = 0; kc < HD; kc += 32){
      bf16x8 af[2], bfr[4];
      #pragma unroll
      for(int mi = 0; mi < 2; ++mi){
        int r = m0 + mi*16 + lr;
        af[mi] = (r < NHEDGE) ? *(const bf16x8*)&xb[(size_t)r*HD + kc + lk] : zero8;
      }
      #pragma unroll
      for(int ni = 0; ni < 4; ++ni){
        int c = n0 + ni*16 + lr;
        bfr[ni] = *(const bf16x8*)&Wb0[(size_t)c*HD + kc + lk];
      }
      #pragma unroll
      for(int mi = 0; mi < 2; ++mi)
        #pragma unroll
        for(int ni = 0; ni < 4; ++ni)
          acc[mi][ni] = __builtin_amdgcn_mfma_f32_16x16x32_bf16(af[mi], bfr[ni], acc[mi][ni], 0, 0, 0);
    }
    #pragma unroll
    for(int mi = 0; mi < 2; ++mi){
      #pragma unroll
      for(int jj = 0; jj < 4; ++jj){
        int r = m0 + mi*16 + rb + jj;
        if(r < NHEDGE){
          float ra = aggw[r];
          float inv = 1.f / hrs[r];
          #pragma unroll
          for(int ni = 0; ni < 4; ++ni){
            int c = n0 + ni*16 + lr;
            float v = (acc[mi][ni][jj] + ra*bc[c]) * inv;
            v = prelu(v, alpha);
            out_ef[(size_t)r*HD + c] = v;
            ef_b[(size_t)r*HD + c] = f2bf(v);
          }
        }
      }
    }
  }
  __syncthreads();   // ef_b rows of this block now visible to this block
  // ---- phase B ----
  for(int n0 = 0; n0 < HD; n0 += 64){
    f32x4 acc[2][4];
    #pragma unroll
    for(int a = 0; a < 2; ++a)
      #pragma unroll
      for(int b = 0; b < 4; ++b) acc[a][b] = (f32x4){0.f,0.f,0.f,0.f};
    #pragma unroll
    for(int kc = 0; kc < HD; kc += 32){
      bf16x8 af[2], bfr[4];
      #pragma unroll
      for(int mi = 0; mi < 2; ++mi){
        int r = m0 + mi*16 + lr;
        af[mi] = (r < NHEDGE) ? *(const bf16x8*)&ef_b[(size_t)r*HD + kc + lk] : zero8;
      }
      #pragma unroll
      for(int ni = 0; ni < 4; ++ni){
        int c = n0 + ni*16 + lr;
        bfr[ni] = *(const bf16x8*)&Wb1[(size_t)c*HD + kc + lk];
      }
      #pragma unroll
      for(int mi = 0; mi < 2; ++mi)
        #pragma unroll
        for(int ni = 0; ni < 4; ++ni)
          acc[mi][ni] = __builtin_amdgcn_mfma_f32_16x16x32_bf16(af[mi], bfr[ni], acc[mi][ni], 0, 0, 0);
    }
    #pragma unroll
    for(int mi = 0; mi < 2; ++mi){
      #pragma unroll
      for(int jj = 0; jj < 4; ++jj){
        int r = m0 + mi*16 + rb + jj;
        if(r < NHEDGE){
          float ra = hrw[r];
          #pragma unroll
          for(int ni = 0; ni < 4; ++ni){
            int c = n0 + ni*16 + lr;
            float v = ra * (acc[mi][ni][jj] + be[c]);
            y_b[(size_t)r*HD + c] = f2bf(v);
          }
        }
      }
    }
  }
}

// ---------------------------------------------------------------------------
// Phase-2 aggregation: 2 nodes per wave, 16B/lane, depth-4 prefetch + epilogue.
// ---------------------------------------------------------------------------
__global__ __launch_bounds__(256) void k_agg2(const unsigned short* __restrict__ yb,
        const int* __restrict__ offs, const int* __restrict__ csrc,
        const float* __restrict__ nrs, const float* __restrict__ alpha_p,
        float* __restrict__ out_nodes){
  int wv = threadIdx.x >> 6, lane = threadIdx.x & 63;
  int sub = lane >> 5, sl = lane & 31;
  int i = blockIdx.x*8 + wv*2 + sub;
  int b = offs[NHEDGE + i], cnt = offs[NHEDGE + i + 1] - b;
  const u16x8* tab = (const u16x8*)yb;
  float acc[8] = {0.f,0.f,0.f,0.f,0.f,0.f,0.f,0.f};
  u16x8 z8 = {0,0,0,0,0,0,0,0};
  u16x8 v0=z8, v1=z8, v2=z8, v3=z8;
  if(cnt > 0){ int j = csrc[b];   v0 = tab[(size_t)j*32 + sl]; }
  if(cnt > 1){ int j = csrc[b+1]; v1 = tab[(size_t)j*32 + sl]; }
  if(cnt > 2){ int j = csrc[b+2]; v2 = tab[(size_t)j*32 + sl]; }
  if(cnt > 3){ int j = csrc[b+3]; v3 = tab[(size_t)j*32 + sl]; }
  int k = 0;
  while(k < cnt){
    { u16x8 cv = v0;
      if(k + 4 < cnt){ int j = csrc[b+k+4]; v0 = tab[(size_t)j*32 + sl]; }
      #pragma unroll
      for(int c = 0; c < 8; ++c) acc[c] += bf2f(cv[c]); }
    if(++k >= cnt) break;
    { u16x8 cv = v1;
      if(k + 4 < cnt){ int j = csrc[b+k+4]; v1 = tab[(size_t)j*32 + sl]; }
      #pragma unroll
      for(int c = 0; c < 8; ++c) acc[c] += bf2f(cv[c]); }
    if(++k >= cnt) break;
    { u16x8 cv = v2;
      if(k + 4 < cnt){ int j = csrc[b+k+4]; v2 = tab[(size_t)j*32 + sl]; }
      #pragma unroll
      for(int c = 0; c < 8; ++c) acc[c] += bf2f(cv[c]); }
    if(++k >= cnt) break;
    { u16x8 cv = v3;
      if(k + 4 < cnt){ int j = csrc[b+k+4]; v3 = tab[(size_t)j*32 + sl]; }
      #pragma unroll
      for(int c = 0; c < 8; ++c) acc[c] += bf2f(cv[c]); }
    ++k;
  }
  float inv = 1.f / nrs[i];
  float a = *alpha_p;
  float4 o1, o2;
  o1.x = prelu(acc[0]*inv, a); o1.y = prelu(acc[1]*inv, a);
  o1.z = prelu(acc[2]*inv, a); o1.w = prelu(acc[3]*inv, a);
  o2.x = prelu(acc[4]*inv, a); o2.y = prelu(acc[5]*inv, a);
  o2.z = prelu(acc[6]*inv, a); o2.w = prelu(acc[7]*inv, a);
  *(float4*)&out_nodes[(size_t)i*HD + sl*8]     = o1;
  *(float4*)&out_nodes[(size_t)i*HD + sl*8 + 4] = o2;
}

// ---------------------------------------------------------------------------
extern "C" void kernel_launch(void* const* d_in, const int* in_sizes, int n_in,
                              void* d_out, int out_size, void* d_ws, size_t ws_size,
                              hipStream_t stream){
  const float* n_feat   = (const float*)d_in[0];
  const int*   node_idx  = (const int*)d_in[2];
  const int*   hedge_idx = (const int*)d_in[3];
  const float* nrw  = (const float*)d_in[4];
  const float* nrs  = (const float*)d_in[5];
  const float* hrw  = (const float*)d_in[6];
  const float* hrs  = (const float*)d_in[7];
  const float* W_in  = (const float*)d_in[8];
  const float* b_in  = (const float*)d_in[9];
  const float* W_n2e = (const float*)d_in[10];
  const float* b_n2e = (const float*)d_in[11];
  const float* W_e2n = (const float*)d_in[12];
  const float* b_e2n = (const float*)d_in[13];
  const float* alpha = (const float*)d_in[14];

  float* out_nodes = (float*)d_out;
  float* out_efeat = out_nodes + (size_t)NNODE * HD;

  // bf16 pre-scaled n_feat table lives in the out_nodes region of d_out: it is
  // consumed only by k_agg1, and k_agg2 (the last kernel) fully overwrites it.
  unsigned short* tabw = (unsigned short*)out_nodes;

  char* p = (char*)d_ws;
  auto take = [&](size_t bytes) -> void* {
    void* r = (void*)p;
    p += (bytes + 255) & ~(size_t)255;
    return r;
  };
  unsigned short* Wb0     = (unsigned short*)take((size_t)HD*HD*2);
  unsigned short* Wb1     = (unsigned short*)take((size_t)HD*HD*2);
  float*          bc      = (float*)take(HD*4);
  float*          aggw    = (float*)take(NHEDGE*4);
  unsigned short* aggx_b  = (unsigned short*)take((size_t)NHEDGE*HD*2);  // aliased as ybuf_b
  unsigned short* efeat_b = (unsigned short*)take((size_t)NHEDGE*HD*2);
  int*            offs    = (int*)take((NS+1)*4);
  int*            cnts    = (int*)take((size_t)NS*4);
  int*            pos     = (int*)take((size_t)NS*4);
  int*            bsum    = (int*)take(SCAN_B*4);
  int*            csrc    = (int*)take((size_t)2*NEDGE*4);
  unsigned short* ybuf_b  = aggx_b;  // safe alias: see k_gemm01 header comment

  k_wprep<<<HD, 256, 0, stream>>>(W_in, b_in, W_n2e, b_n2e, W_e2n, Wb0, Wb1, bc, cnts, pos);
  k_cvthist<<<CVT_B + HIST_B, 256, 0, stream>>>(n_feat, nrw, node_idx, hedge_idx, tabw, cnts);
  k_scanA<<<SCAN_B, 256, 0, stream>>>(cnts, bsum);
  k_scanC<<<SCAN_B, 256, 0, stream>>>(cnts, bsum, offs);
  k_fill<<<HIST_B, 256, 0, stream>>>(node_idx, hedge_idx, offs, pos, csrc);
  k_agg1<<<NHEDGE/8, 256, 0, stream>>>(tabw, nrw, offs, csrc, aggx_b, aggw);
  k_gemm01<<<(NHEDGE + 127)/128, 256, 0, stream>>>(aggx_b, Wb0, Wb1, aggw, hrs, hrw,
                                                   bc, b_e2n, alpha,
                                                   out_efeat, efeat_b, ybuf_b);
  k_agg2<<<NNODE/8, 256, 0, stream>>>(ybuf_b, offs, csrc, nrs, alpha, out_nodes);
}

// Round 7
// 181.068 us; speedup vs baseline: 1.1756x; 1.1756x over previous
//
#include <hip/hip_runtime.h>

#define NNODE  50000
#define NHEDGE 10000
#define NEDGE  300000
#define HD     256
#define NS     (NHEDGE + NNODE)   // 60000 combined segments
#define SCAN_B 59                 // ceil(NS/1024)
#define CVT_B  ((NNODE * HD) / (256 * 8))   // 6250
#define HIST_B ((NEDGE + 255) / 256)        // 1172

typedef __attribute__((ext_vector_type(8))) short bf16x8;
typedef __attribute__((ext_vector_type(8))) unsigned short u16x8;
typedef __attribute__((ext_vector_type(4))) float f32x4;

__device__ __forceinline__ float prelu(float v, float a){ return v > 0.f ? v : a*v; }
__device__ __forceinline__ unsigned short f2bf(float f){
  unsigned u = __float_as_uint(f);
  return (unsigned short)((u + 0x7FFFu + ((u>>16)&1u)) >> 16);   // RNE
}
__device__ __forceinline__ float bf2f(unsigned short h){
  return __uint_as_float(((unsigned)h) << 16);
}

// ---------------------------------------------------------------------------
// Weight prep, one block per output row o:
//   Wb0[o][i] = bf16( sum_h W_n2e[o][h]*W_in[h][i] )   (B for GEMM0, [n][k])
//   Wb1[o][i] = bf16( W_e2n[o][i] )                    (B for GEMM1, [n][k])
//   bc[o]     = dot(W_n2e[o,:], b_in) + b_n2e[o]       (LDS reduce)
//   also zeroes cnts[] and pos[] (65536 threads >= NS each)
// ---------------------------------------------------------------------------
__global__ __launch_bounds__(256) void k_wprep(
    const float* __restrict__ W_in, const float* __restrict__ b_in,
    const float* __restrict__ W_n2e, const float* __restrict__ b_n2e,
    const float* __restrict__ W_e2n,
    unsigned short* __restrict__ Wb0, unsigned short* __restrict__ Wb1,
    float* __restrict__ bc, int* __restrict__ cnts, int* __restrict__ pos){
  int o = blockIdx.x, t = threadIdx.x;
  int zi = o*256 + t;
  if(zi < NS){ cnts[zi] = 0; pos[zi] = 0; }
  __shared__ float wn[HD];
  __shared__ float red[4];
  wn[t] = W_n2e[(size_t)o*HD + t];
  __syncthreads();
  float pb = wn[t] * b_in[t];
  #pragma unroll
  for(int d = 32; d > 0; d >>= 1) pb += __shfl_down(pb, d);
  if((t & 63) == 0) red[t >> 6] = pb;
  float acc = 0.f;
  #pragma unroll 8
  for(int h = 0; h < HD; ++h) acc += wn[h] * W_in[(size_t)h*HD + t];
  Wb0[(size_t)o*HD + t] = f2bf(acc);
  Wb1[(size_t)o*HD + t] = f2bf(W_e2n[(size_t)o*HD + t]);
  __syncthreads();
  if(t == 0) bc[o] = red[0] + red[1] + red[2] + red[3] + b_n2e[o];
}

// ---------------------------------------------------------------------------
// Merged: [0, CVT_B) blocks convert n_feat -> pre-scaled bf16 table
//         [CVT_B, CVT_B+HIST_B) blocks do the combined segment histogram
// ---------------------------------------------------------------------------
__global__ __launch_bounds__(256) void k_cvthist(
    const float* __restrict__ n_feat, const float* __restrict__ nrw,
    const int* __restrict__ node_idx, const int* __restrict__ hedge_idx,
    unsigned short* __restrict__ tabw, int* __restrict__ cnts){
  int blk = blockIdx.x, t = threadIdx.x;
  if(blk < CVT_B){
    size_t i8 = (size_t)blk*256 + t;
    int row = (int)(i8 >> 5);            // 32 x u16x8 per 256-col row
    float w = nrw[row];
    const float4* f4 = (const float4*)n_feat;
    float4 a = f4[i8*2], c = f4[i8*2 + 1];
    u16x8 o;
    o[0] = f2bf(w*a.x); o[1] = f2bf(w*a.y); o[2] = f2bf(w*a.z); o[3] = f2bf(w*a.w);
    o[4] = f2bf(w*c.x); o[5] = f2bf(w*c.y); o[6] = f2bf(w*c.z); o[7] = f2bf(w*c.w);
    ((u16x8*)tabw)[i8] = o;
  } else {
    int e = (blk - CVT_B)*256 + t;
    if(e < NEDGE){
      atomicAdd(&cnts[hedge_idx[e]], 1);
      atomicAdd(&cnts[NHEDGE + node_idx[e]], 1);
    }
  }
}

// ---------------------------------------------------------------------------
// Scan step A: per-1024-chunk block sums
// ---------------------------------------------------------------------------
__global__ __launch_bounds__(256) void k_scanA(const int* __restrict__ cnts, int* __restrict__ bsum){
  int idx4 = blockIdx.x*256 + threadIdx.x;
  int4 v = make_int4(0,0,0,0);
  if(idx4 < NS/4) v = ((const int4*)cnts)[idx4];
  int s = v.x + v.y + v.z + v.w;
  __shared__ int red[256];
  red[threadIdx.x] = s; __syncthreads();
  for(int d = 128; d > 0; d >>= 1){
    if(threadIdx.x < d) red[threadIdx.x] += red[threadIdx.x + d];
    __syncthreads();
  }
  if(threadIdx.x == 0) bsum[blockIdx.x] = red[0];
}

// ---------------------------------------------------------------------------
// Scan step C (scanB inlined): wave 0 reduces bsum[0:blockIdx) for the block
// prefix, then the block emits its 1024 exclusive offsets.
// ---------------------------------------------------------------------------
__global__ __launch_bounds__(256) void k_scanC(const int* __restrict__ cnts,
        const int* __restrict__ bsum, int* __restrict__ offs){
  __shared__ int base_s;
  __shared__ int sc[256];
  int t = threadIdx.x;
  if(t < 64){
    int v = (t < (int)blockIdx.x) ? bsum[t] : 0;   // blockIdx.x <= 58 < 64
    #pragma unroll
    for(int d = 32; d > 0; d >>= 1) v += __shfl_down(v, d);
    if(t == 0) base_s = v;
  }
  int idx4 = blockIdx.x*256 + t;
  int4 v4 = make_int4(0,0,0,0);
  if(idx4 < NS/4) v4 = ((const int4*)cnts)[idx4];
  int s = v4.x + v4.y + v4.z + v4.w;
  sc[t] = s; __syncthreads();
  for(int d = 1; d < 256; d <<= 1){
    int q = (t >= d) ? sc[t-d] : 0; __syncthreads();
    sc[t] += q; __syncthreads();
  }
  int excl = sc[t] - s + base_s;
  int base = idx4*4;
  if(base < NS){
    int r = excl;
    offs[base]   = r; r += v4.x;
    offs[base+1] = r; r += v4.y;
    offs[base+2] = r; r += v4.z;
    offs[base+3] = r;
  }
  if(blockIdx.x == 0 && t == 0) offs[NS] = 2*NEDGE;   // total is a known constant
}

// ---------------------------------------------------------------------------
// Fill CSR buckets (hedge buckets in csrc[0..NEDGE), node buckets after).
// ---------------------------------------------------------------------------
__global__ void k_fill(const int* __restrict__ node_idx, const int* __restrict__ hedge_idx,
                       const int* __restrict__ offs, int* __restrict__ pos,
                       int* __restrict__ csrc){
  int e = blockIdx.x*256 + threadIdx.x;
  if(e < NEDGE){
    int j = hedge_idx[e];
    int n = node_idx[e];
    int p = offs[j] + atomicAdd(&pos[j], 1);
    csrc[p] = n;
    int q = offs[NHEDGE + n] + atomicAdd(&pos[NHEDGE + n], 1);
    csrc[q] = j;
  }
}

// ---------------------------------------------------------------------------
// Phase-1 aggregation: 2 hedges per wave (32 lanes each), 16B/lane (u16x8),
// depth-4 prefetch.
// ---------------------------------------------------------------------------
__global__ __launch_bounds__(256) void k_agg1(const unsigned short* __restrict__ tabw,
        const float* __restrict__ nrw,
        const int* __restrict__ offs, const int* __restrict__ csrc,
        unsigned short* __restrict__ aggx_b, float* __restrict__ aggw){
  int wv = threadIdx.x >> 6, lane = threadIdx.x & 63;
  int sub = lane >> 5, sl = lane & 31;
  int j = blockIdx.x*8 + wv*2 + sub;
  int b = offs[j], cnt = offs[j+1] - b;
  const u16x8* tab = (const u16x8*)tabw;   // 32 x u16x8 per row
  float acc[8] = {0.f,0.f,0.f,0.f,0.f,0.f,0.f,0.f};
  float sw = 0.f;
  u16x8 z8 = {0,0,0,0,0,0,0,0};
  u16x8 v0=z8, v1=z8, v2=z8, v3=z8;
  float w0=0.f, w1=0.f, w2=0.f, w3=0.f;
  if(cnt > 0){ int n = csrc[b];   w0 = nrw[n]; v0 = tab[(size_t)n*32 + sl]; }
  if(cnt > 1){ int n = csrc[b+1]; w1 = nrw[n]; v1 = tab[(size_t)n*32 + sl]; }
  if(cnt > 2){ int n = csrc[b+2]; w2 = nrw[n]; v2 = tab[(size_t)n*32 + sl]; }
  if(cnt > 3){ int n = csrc[b+3]; w3 = nrw[n]; v3 = tab[(size_t)n*32 + sl]; }
  int k = 0;
  while(k < cnt){
    { u16x8 cv = v0; float cw = w0;
      if(k + 4 < cnt){ int n = csrc[b+k+4]; w0 = nrw[n]; v0 = tab[(size_t)n*32 + sl]; }
      #pragma unroll
      for(int c = 0; c < 8; ++c) acc[c] += bf2f(cv[c]);
      sw += cw; }
    if(++k >= cnt) break;
    { u16x8 cv = v1; float cw = w1;
      if(k + 4 < cnt){ int n = csrc[b+k+4]; w1 = nrw[n]; v1 = tab[(size_t)n*32 + sl]; }
      #pragma unroll
      for(int c = 0; c < 8; ++c) acc[c] += bf2f(cv[c]);
      sw += cw; }
    if(++k >= cnt) break;
    { u16x8 cv = v2; float cw = w2;
      if(k + 4 < cnt){ int n = csrc[b+k+4]; w2 = nrw[n]; v2 = tab[(size_t)n*32 + sl]; }
      #pragma unroll
      for(int c = 0; c < 8; ++c) acc[c] += bf2f(cv[c]);
      sw += cw; }
    if(++k >= cnt) break;
    { u16x8 cv = v3; float cw = w3;
      if(k + 4 < cnt){ int n = csrc[b+k+4]; w3 = nrw[n]; v3 = tab[(size_t)n*32 + sl]; }
      #pragma unroll
      for(int c = 0; c < 8; ++c) acc[c] += bf2f(cv[c]);
      sw += cw; }
    ++k;
  }
  u16x8 ob;
  #pragma unroll
  for(int c = 0; c < 8; ++c) ob[c] = f2bf(acc[c]);
  ((u16x8*)aggx_b)[(size_t)j*32 + sl] = ob;
  if(sl == 0) aggw[j] = sw;
}

// ---------------------------------------------------------------------------
// Fused GEMM0+GEMM1, 32 rows per block (grid = 313 blocks for parallelism).
// The block's 4 waves each own one 64-col tile; together they cover all 256
// cols of the block's 32 rows in phase A, then after __syncthreads each wave
// computes its 64-col tile of y from the block's (L2-hot) ef_b rows.
// Phase A: efeat = prelu((aggx@Wc^T + aggw*bc)/hrs) -> out_ef (f32) + ef_b (bf16)
// Phase B: y = hrw*(efeat@W_e2n^T + be)             -> y_b (bf16)
// y_b aliases aggx_b: a block writes only the rows it owns, after its phase-A
// reads of those same rows completed (barrier drains loads) -> no hazard.
// ---------------------------------------------------------------------------
__global__ __launch_bounds__(256) void k_gemm01(
    const unsigned short* __restrict__ xb, const unsigned short* __restrict__ Wb0,
    const unsigned short* __restrict__ Wb1,
    const float* __restrict__ aggw, const float* __restrict__ hrs,
    const float* __restrict__ hrw, const float* __restrict__ bc,
    const float* __restrict__ be, const float* __restrict__ alpha_p,
    float* __restrict__ out_ef, unsigned short* __restrict__ ef_b,
    unsigned short* __restrict__ y_b){
  int wv = threadIdx.x >> 6, lane = threadIdx.x & 63;
  int m0 = blockIdx.x*32;        // block's 32 rows
  int n0 = wv*64;                // wave's 64-col tile
  int lr = lane & 15, lk = (lane >> 4) << 3, rb = (lane >> 4) << 2;
  float alpha = *alpha_p;
  const bf16x8 zero8 = {0,0,0,0,0,0,0,0};
  // ---- phase A ----
  {
    f32x4 acc[2][4];
    #pragma unroll
    for(int a = 0; a < 2; ++a)
      #pragma unroll
      for(int b = 0; b < 4; ++b) acc[a][b] = (f32x4){0.f,0.f,0.f,0.f};
    #pragma unroll
    for(int kc = 0; kc < HD; kc += 32){
      bf16x8 af[2], bfr[4];
      #pragma unroll
      for(int mi = 0; mi < 2; ++mi){
        int r = m0 + mi*16 + lr;
        af[mi] = (r < NHEDGE) ? *(const bf16x8*)&xb[(size_t)r*HD + kc + lk] : zero8;
      }
      #pragma unroll
      for(int ni = 0; ni < 4; ++ni){
        int c = n0 + ni*16 + lr;
        bfr[ni] = *(const bf16x8*)&Wb0[(size_t)c*HD + kc + lk];
      }
      #pragma unroll
      for(int mi = 0; mi < 2; ++mi)
        #pragma unroll
        for(int ni = 0; ni < 4; ++ni)
          acc[mi][ni] = __builtin_amdgcn_mfma_f32_16x16x32_bf16(af[mi], bfr[ni], acc[mi][ni], 0, 0, 0);
    }
    #pragma unroll
    for(int mi = 0; mi < 2; ++mi){
      #pragma unroll
      for(int jj = 0; jj < 4; ++jj){
        int r = m0 + mi*16 + rb + jj;
        if(r < NHEDGE){
          float ra = aggw[r];
          float inv = 1.f / hrs[r];
          #pragma unroll
          for(int ni = 0; ni < 4; ++ni){
            int c = n0 + ni*16 + lr;
            float v = (acc[mi][ni][jj] + ra*bc[c]) * inv;
            v = prelu(v, alpha);
            out_ef[(size_t)r*HD + c] = v;
            ef_b[(size_t)r*HD + c] = f2bf(v);
          }
        }
      }
    }
  }
  __syncthreads();   // block's ef_b rows visible (stores drained to L2)
  // ---- phase B ----
  {
    f32x4 acc[2][4];
    #pragma unroll
    for(int a = 0; a < 2; ++a)
      #pragma unroll
      for(int b = 0; b < 4; ++b) acc[a][b] = (f32x4){0.f,0.f,0.f,0.f};
    #pragma unroll
    for(int kc = 0; kc < HD; kc += 32){
      bf16x8 af[2], bfr[4];
      #pragma unroll
      for(int mi = 0; mi < 2; ++mi){
        int r = m0 + mi*16 + lr;
        af[mi] = (r < NHEDGE) ? *(const bf16x8*)&ef_b[(size_t)r*HD + kc + lk] : zero8;
      }
      #pragma unroll
      for(int ni = 0; ni < 4; ++ni){
        int c = n0 + ni*16 + lr;
        bfr[ni] = *(const bf16x8*)&Wb1[(size_t)c*HD + kc + lk];
      }
      #pragma unroll
      for(int mi = 0; mi < 2; ++mi)
        #pragma unroll
        for(int ni = 0; ni < 4; ++ni)
          acc[mi][ni] = __builtin_amdgcn_mfma_f32_16x16x32_bf16(af[mi], bfr[ni], acc[mi][ni], 0, 0, 0);
    }
    #pragma unroll
    for(int mi = 0; mi < 2; ++mi){
      #pragma unroll
      for(int jj = 0; jj < 4; ++jj){
        int r = m0 + mi*16 + rb + jj;
        if(r < NHEDGE){
          float ra = hrw[r];
          #pragma unroll
          for(int ni = 0; ni < 4; ++ni){
            int c = n0 + ni*16 + lr;
            float v = ra * (acc[mi][ni][jj] + be[c]);
            y_b[(size_t)r*HD + c] = f2bf(v);
          }
        }
      }
    }
  }
}

// ---------------------------------------------------------------------------
// Phase-2 aggregation: 2 nodes per wave, 16B/lane, depth-4 prefetch + epilogue.
// ---------------------------------------------------------------------------
__global__ __launch_bounds__(256) void k_agg2(const unsigned short* __restrict__ yb,
        const int* __restrict__ offs, const int* __restrict__ csrc,
        const float* __restrict__ nrs, const float* __restrict__ alpha_p,
        float* __restrict__ out_nodes){
  int wv = threadIdx.x >> 6, lane = threadIdx.x & 63;
  int sub = lane >> 5, sl = lane & 31;
  int i = blockIdx.x*8 + wv*2 + sub;
  int b = offs[NHEDGE + i], cnt = offs[NHEDGE + i + 1] - b;
  const u16x8* tab = (const u16x8*)yb;
  float acc[8] = {0.f,0.f,0.f,0.f,0.f,0.f,0.f,0.f};
  u16x8 z8 = {0,0,0,0,0,0,0,0};
  u16x8 v0=z8, v1=z8, v2=z8, v3=z8;
  if(cnt > 0){ int j = csrc[b];   v0 = tab[(size_t)j*32 + sl]; }
  if(cnt > 1){ int j = csrc[b+1]; v1 = tab[(size_t)j*32 + sl]; }
  if(cnt > 2){ int j = csrc[b+2]; v2 = tab[(size_t)j*32 + sl]; }
  if(cnt > 3){ int j = csrc[b+3]; v3 = tab[(size_t)j*32 + sl]; }
  int k = 0;
  while(k < cnt){
    { u16x8 cv = v0;
      if(k + 4 < cnt){ int j = csrc[b+k+4]; v0 = tab[(size_t)j*32 + sl]; }
      #pragma unroll
      for(int c = 0; c < 8; ++c) acc[c] += bf2f(cv[c]); }
    if(++k >= cnt) break;
    { u16x8 cv = v1;
      if(k + 4 < cnt){ int j = csrc[b+k+4]; v1 = tab[(size_t)j*32 + sl]; }
      #pragma unroll
      for(int c = 0; c < 8; ++c) acc[c] += bf2f(cv[c]); }
    if(++k >= cnt) break;
    { u16x8 cv = v2;
      if(k + 4 < cnt){ int j = csrc[b+k+4]; v2 = tab[(size_t)j*32 + sl]; }
      #pragma unroll
      for(int c = 0; c < 8; ++c) acc[c] += bf2f(cv[c]); }
    if(++k >= cnt) break;
    { u16x8 cv = v3;
      if(k + 4 < cnt){ int j = csrc[b+k+4]; v3 = tab[(size_t)j*32 + sl]; }
      #pragma unroll
      for(int c = 0; c < 8; ++c) acc[c] += bf2f(cv[c]); }
    ++k;
  }
  float inv = 1.f / nrs[i];
  float a = *alpha_p;
  float4 o1, o2;
  o1.x = prelu(acc[0]*inv, a); o1.y = prelu(acc[1]*inv, a);
  o1.z = prelu(acc[2]*inv, a); o1.w = prelu(acc[3]*inv, a);
  o2.x = prelu(acc[4]*inv, a); o2.y = prelu(acc[5]*inv, a);
  o2.z = prelu(acc[6]*inv, a); o2.w = prelu(acc[7]*inv, a);
  *(float4*)&out_nodes[(size_t)i*HD + sl*8]     = o1;
  *(float4*)&out_nodes[(size_t)i*HD + sl*8 + 4] = o2;
}

// ---------------------------------------------------------------------------
extern "C" void kernel_launch(void* const* d_in, const int* in_sizes, int n_in,
                              void* d_out, int out_size, void* d_ws, size_t ws_size,
                              hipStream_t stream){
  const float* n_feat   = (const float*)d_in[0];
  const int*   node_idx  = (const int*)d_in[2];
  const int*   hedge_idx = (const int*)d_in[3];
  const float* nrw  = (const float*)d_in[4];
  const float* nrs  = (const float*)d_in[5];
  const float* hrw  = (const float*)d_in[6];
  const float* hrs  = (const float*)d_in[7];
  const float* W_in  = (const float*)d_in[8];
  const float* b_in  = (const float*)d_in[9];
  const float* W_n2e = (const float*)d_in[10];
  const float* b_n2e = (const float*)d_in[11];
  const float* W_e2n = (const float*)d_in[12];
  const float* b_e2n = (const float*)d_in[13];
  const float* alpha = (const float*)d_in[14];

  float* out_nodes = (float*)d_out;
  float* out_efeat = out_nodes + (size_t)NNODE * HD;

  // bf16 pre-scaled n_feat table lives in the out_nodes region of d_out: it is
  // consumed only by k_agg1, and k_agg2 (the last kernel) fully overwrites it.
  unsigned short* tabw = (unsigned short*)out_nodes;

  char* p = (char*)d_ws;
  auto take = [&](size_t bytes) -> void* {
    void* r = (void*)p;
    p += (bytes + 255) & ~(size_t)255;
    return r;
  };
  unsigned short* Wb0     = (unsigned short*)take((size_t)HD*HD*2);
  unsigned short* Wb1     = (unsigned short*)take((size_t)HD*HD*2);
  float*          bc      = (float*)take(HD*4);
  float*          aggw    = (float*)take(NHEDGE*4);
  unsigned short* aggx_b  = (unsigned short*)take((size_t)NHEDGE*HD*2);  // aliased as ybuf_b
  unsigned short* efeat_b = (unsigned short*)take((size_t)NHEDGE*HD*2);
  int*            offs    = (int*)take((NS+1)*4);
  int*            cnts    = (int*)take((size_t)NS*4);
  int*            pos     = (int*)take((size_t)NS*4);
  int*            bsum    = (int*)take(SCAN_B*4);
  int*            csrc    = (int*)take((size_t)2*NEDGE*4);
  unsigned short* ybuf_b  = aggx_b;  // safe alias: see k_gemm01 header comment

  k_wprep<<<HD, 256, 0, stream>>>(W_in, b_in, W_n2e, b_n2e, W_e2n, Wb0, Wb1, bc, cnts, pos);
  k_cvthist<<<CVT_B + HIST_B, 256, 0, stream>>>(n_feat, nrw, node_idx, hedge_idx, tabw, cnts);
  k_scanA<<<SCAN_B, 256, 0, stream>>>(cnts, bsum);
  k_scanC<<<SCAN_B, 256, 0, stream>>>(cnts, bsum, offs);
  k_fill<<<HIST_B, 256, 0, stream>>>(node_idx, hedge_idx, offs, pos, csrc);
  k_agg1<<<NHEDGE/8, 256, 0, stream>>>(tabw, nrw, offs, csrc, aggx_b, aggw);
  k_gemm01<<<(NHEDGE + 31)/32, 256, 0, stream>>>(aggx_b, Wb0, Wb1, aggw, hrs, hrw,
                                                 bc, b_e2n, alpha,
                                                 out_efeat, efeat_b, ybuf_b);
  k_agg2<<<NNODE/8, 256, 0, stream>>>(ybuf_b, offs, csrc, nrs, alpha, out_nodes);
}

// Round 8
// 179.210 us; speedup vs baseline: 1.1878x; 1.0104x over previous
//
#include <hip/hip_runtime.h>

#define NNODE  50000
#define NHEDGE 10000
#define NEDGE  300000
#define HD     256
#define NS     (NHEDGE + NNODE)   // 60000 combined segments
#define SCAN_B 59                 // ceil(NS/1024)
#define HIST_B ((NEDGE + 255) / 256)        // 1172
#define PAD    32                 // one counter per 128B line (atomic anti-false-sharing)

typedef __attribute__((ext_vector_type(8))) short bf16x8;
typedef __attribute__((ext_vector_type(8))) unsigned short u16x8;
typedef __attribute__((ext_vector_type(4))) float f32x4;

__device__ __forceinline__ float prelu(float v, float a){ return v > 0.f ? v : a*v; }
__device__ __forceinline__ unsigned short f2bf(float f){
  unsigned u = __float_as_uint(f);
  return (unsigned short)((u + 0x7FFFu + ((u>>16)&1u)) >> 16);   // RNE
}
__device__ __forceinline__ float bf2f(unsigned short h){
  return __uint_as_float(((unsigned)h) << 16);
}

// ---------------------------------------------------------------------------
// Weight prep, one block per output row o:
//   Wb0[o][i] = bf16( sum_h W_n2e[o][h]*W_in[h][i] )   (B for GEMM0, [n][k])
//   Wb1[o][i] = bf16( W_e2n[o][i] )                    (B for GEMM1, [n][k])
//   bc[o]     = dot(W_n2e[o,:], b_in) + b_n2e[o]       (LDS reduce)
//   also zeroes the live slots of padded cnts[] / pos[]
// ---------------------------------------------------------------------------
__global__ __launch_bounds__(256) void k_wprep(
    const float* __restrict__ W_in, const float* __restrict__ b_in,
    const float* __restrict__ W_n2e, const float* __restrict__ b_n2e,
    const float* __restrict__ W_e2n,
    unsigned short* __restrict__ Wb0, unsigned short* __restrict__ Wb1,
    float* __restrict__ bc, int* __restrict__ cnts, int* __restrict__ pos){
  int o = blockIdx.x, t = threadIdx.x;
  int zi = o*256 + t;
  if(zi < NS){ cnts[(size_t)zi*PAD] = 0; pos[(size_t)zi*PAD] = 0; }
  __shared__ float wn[HD];
  __shared__ float red[4];
  wn[t] = W_n2e[(size_t)o*HD + t];
  __syncthreads();
  float pb = wn[t] * b_in[t];
  #pragma unroll
  for(int d = 32; d > 0; d >>= 1) pb += __shfl_down(pb, d);
  if((t & 63) == 0) red[t >> 6] = pb;
  float acc = 0.f;
  #pragma unroll 8
  for(int h = 0; h < HD; ++h) acc += wn[h] * W_in[(size_t)h*HD + t];
  Wb0[(size_t)o*HD + t] = f2bf(acc);
  Wb1[(size_t)o*HD + t] = f2bf(W_e2n[(size_t)o*HD + t]);
  __syncthreads();
  if(t == 0) bc[o] = red[0] + red[1] + red[2] + red[3] + b_n2e[o];
}

// ---------------------------------------------------------------------------
// n_feat f32 -> pre-scaled bf16 table. 32 elems per thread: 8 independent
// float4 loads in flight (128B/lane) -> latency-tolerant streaming.
// Each thread's 32 elems lie in one row (32 | 256).
// ---------------------------------------------------------------------------
__global__ __launch_bounds__(256) void k_cvt(const float* __restrict__ n_feat,
                                             const float* __restrict__ nrw,
                                             unsigned short* __restrict__ tabw){
  int t32 = blockIdx.x*256 + threadIdx.x;
  if(t32 >= (NNODE*HD)/32) return;
  size_t f = (size_t)t32 * 32;
  float w = nrw[f >> 8];
  const float4* f4 = (const float4*)(n_feat + f);
  float4 a0 = f4[0], a1 = f4[1], a2 = f4[2], a3 = f4[3];
  float4 a4 = f4[4], a5 = f4[5], a6 = f4[6], a7 = f4[7];
  u16x8* out = (u16x8*)(tabw + f);
  u16x8 o0, o1, o2, o3;
  o0[0]=f2bf(w*a0.x); o0[1]=f2bf(w*a0.y); o0[2]=f2bf(w*a0.z); o0[3]=f2bf(w*a0.w);
  o0[4]=f2bf(w*a1.x); o0[5]=f2bf(w*a1.y); o0[6]=f2bf(w*a1.z); o0[7]=f2bf(w*a1.w);
  o1[0]=f2bf(w*a2.x); o1[1]=f2bf(w*a2.y); o1[2]=f2bf(w*a2.z); o1[3]=f2bf(w*a2.w);
  o1[4]=f2bf(w*a3.x); o1[5]=f2bf(w*a3.y); o1[6]=f2bf(w*a3.z); o1[7]=f2bf(w*a3.w);
  o2[0]=f2bf(w*a4.x); o2[1]=f2bf(w*a4.y); o2[2]=f2bf(w*a4.z); o2[3]=f2bf(w*a4.w);
  o2[4]=f2bf(w*a5.x); o2[5]=f2bf(w*a5.y); o2[6]=f2bf(w*a5.z); o2[7]=f2bf(w*a5.w);
  o3[0]=f2bf(w*a6.x); o3[1]=f2bf(w*a6.y); o3[2]=f2bf(w*a6.z); o3[3]=f2bf(w*a6.w);
  o3[4]=f2bf(w*a7.x); o3[5]=f2bf(w*a7.y); o3[6]=f2bf(w*a7.z); o3[7]=f2bf(w*a7.w);
  out[0] = o0; out[1] = o1; out[2] = o2; out[3] = o3;
}

// ---------------------------------------------------------------------------
// Combined histogram into PADDED counters (1 counter / 128B line).
// ---------------------------------------------------------------------------
__global__ void k_hist(const int* __restrict__ node_idx, const int* __restrict__ hedge_idx,
                       int* __restrict__ cnts){
  int e = blockIdx.x*256 + threadIdx.x;
  if(e < NEDGE){
    atomicAdd(&cnts[(size_t)hedge_idx[e]*PAD], 1);
    atomicAdd(&cnts[(size_t)(NHEDGE + node_idx[e])*PAD], 1);
  }
}

// ---------------------------------------------------------------------------
// Scan step A: per-1024-chunk block sums (strided reads from padded cnts)
// ---------------------------------------------------------------------------
__global__ __launch_bounds__(256) void k_scanA(const int* __restrict__ cnts, int* __restrict__ bsum){
  int idx4 = blockIdx.x*256 + threadIdx.x;
  int s = 0;
  if(idx4 < NS/4){
    int b0 = idx4*4;
    s = cnts[(size_t)b0*PAD] + cnts[(size_t)(b0+1)*PAD]
      + cnts[(size_t)(b0+2)*PAD] + cnts[(size_t)(b0+3)*PAD];
  }
  __shared__ int red[256];
  red[threadIdx.x] = s; __syncthreads();
  for(int d = 128; d > 0; d >>= 1){
    if(threadIdx.x < d) red[threadIdx.x] += red[threadIdx.x + d];
    __syncthreads();
  }
  if(threadIdx.x == 0) bsum[blockIdx.x] = red[0];
}

// ---------------------------------------------------------------------------
// Scan step C: wave 0 reduces bsum[0:blockIdx) for the block prefix, then the
// block emits its 1024 exclusive offsets (offs is unpadded).
// ---------------------------------------------------------------------------
__global__ __launch_bounds__(256) void k_scanC(const int* __restrict__ cnts,
        const int* __restrict__ bsum, int* __restrict__ offs){
  __shared__ int base_s;
  __shared__ int sc[256];
  int t = threadIdx.x;
  if(t < 64){
    int v = (t < (int)blockIdx.x) ? bsum[t] : 0;   // blockIdx.x <= 58 < 64
    #pragma unroll
    for(int d = 32; d > 0; d >>= 1) v += __shfl_down(v, d);
    if(t == 0) base_s = v;
  }
  int idx4 = blockIdx.x*256 + t;
  int4 v4 = make_int4(0,0,0,0);
  if(idx4 < NS/4){
    int b0 = idx4*4;
    v4.x = cnts[(size_t)b0*PAD];     v4.y = cnts[(size_t)(b0+1)*PAD];
    v4.z = cnts[(size_t)(b0+2)*PAD]; v4.w = cnts[(size_t)(b0+3)*PAD];
  }
  int s = v4.x + v4.y + v4.z + v4.w;
  sc[t] = s; __syncthreads();
  for(int d = 1; d < 256; d <<= 1){
    int q = (t >= d) ? sc[t-d] : 0; __syncthreads();
    sc[t] += q; __syncthreads();
  }
  int excl = sc[t] - s + base_s;
  int base = idx4*4;
  if(base < NS){
    int r = excl;
    offs[base]   = r; r += v4.x;
    offs[base+1] = r; r += v4.y;
    offs[base+2] = r; r += v4.z;
    offs[base+3] = r;
  }
  if(blockIdx.x == 0 && t == 0) offs[NS] = 2*NEDGE;
}

// ---------------------------------------------------------------------------
// Fill CSR buckets; pos is padded (atomic anti-false-sharing).
// ---------------------------------------------------------------------------
__global__ void k_fill(const int* __restrict__ node_idx, const int* __restrict__ hedge_idx,
                       const int* __restrict__ offs, int* __restrict__ pos,
                       int* __restrict__ csrc){
  int e = blockIdx.x*256 + threadIdx.x;
  if(e < NEDGE){
    int j = hedge_idx[e];
    int n = node_idx[e];
    int p = offs[j] + atomicAdd(&pos[(size_t)j*PAD], 1);
    csrc[p] = n;
    int q = offs[NHEDGE + n] + atomicAdd(&pos[(size_t)(NHEDGE + n)*PAD], 1);
    csrc[q] = j;
  }
}

// ---------------------------------------------------------------------------
// Phase-1 aggregation: 2 hedges per wave (32 lanes each), 16B/lane (u16x8),
// depth-4 prefetch.
// ---------------------------------------------------------------------------
__global__ __launch_bounds__(256) void k_agg1(const unsigned short* __restrict__ tabw,
        const float* __restrict__ nrw,
        const int* __restrict__ offs, const int* __restrict__ csrc,
        unsigned short* __restrict__ aggx_b, float* __restrict__ aggw){
  int wv = threadIdx.x >> 6, lane = threadIdx.x & 63;
  int sub = lane >> 5, sl = lane & 31;
  int j = blockIdx.x*8 + wv*2 + sub;
  int b = offs[j], cnt = offs[j+1] - b;
  const u16x8* tab = (const u16x8*)tabw;   // 32 x u16x8 per row
  float acc[8] = {0.f,0.f,0.f,0.f,0.f,0.f,0.f,0.f};
  float sw = 0.f;
  u16x8 z8 = {0,0,0,0,0,0,0,0};
  u16x8 v0=z8, v1=z8, v2=z8, v3=z8;
  float w0=0.f, w1=0.f, w2=0.f, w3=0.f;
  if(cnt > 0){ int n = csrc[b];   w0 = nrw[n]; v0 = tab[(size_t)n*32 + sl]; }
  if(cnt > 1){ int n = csrc[b+1]; w1 = nrw[n]; v1 = tab[(size_t)n*32 + sl]; }
  if(cnt > 2){ int n = csrc[b+2]; w2 = nrw[n]; v2 = tab[(size_t)n*32 + sl]; }
  if(cnt > 3){ int n = csrc[b+3]; w3 = nrw[n]; v3 = tab[(size_t)n*32 + sl]; }
  int k = 0;
  while(k < cnt){
    { u16x8 cv = v0; float cw = w0;
      if(k + 4 < cnt){ int n = csrc[b+k+4]; w0 = nrw[n]; v0 = tab[(size_t)n*32 + sl]; }
      #pragma unroll
      for(int c = 0; c < 8; ++c) acc[c] += bf2f(cv[c]);
      sw += cw; }
    if(++k >= cnt) break;
    { u16x8 cv = v1; float cw = w1;
      if(k + 4 < cnt){ int n = csrc[b+k+4]; w1 = nrw[n]; v1 = tab[(size_t)n*32 + sl]; }
      #pragma unroll
      for(int c = 0; c < 8; ++c) acc[c] += bf2f(cv[c]);
      sw += cw; }
    if(++k >= cnt) break;
    { u16x8 cv = v2; float cw = w2;
      if(k + 4 < cnt){ int n = csrc[b+k+4]; w2 = nrw[n]; v2 = tab[(size_t)n*32 + sl]; }
      #pragma unroll
      for(int c = 0; c < 8; ++c) acc[c] += bf2f(cv[c]);
      sw += cw; }
    if(++k >= cnt) break;
    { u16x8 cv = v3; float cw = w3;
      if(k + 4 < cnt){ int n = csrc[b+k+4]; w3 = nrw[n]; v3 = tab[(size_t)n*32 + sl]; }
      #pragma unroll
      for(int c = 0; c < 8; ++c) acc[c] += bf2f(cv[c]);
      sw += cw; }
    ++k;
  }
  u16x8 ob;
  #pragma unroll
  for(int c = 0; c < 8; ++c) ob[c] = f2bf(acc[c]);
  ((u16x8*)aggx_b)[(size_t)j*32 + sl] = ob;
  if(sl == 0) aggw[j] = sw;
}

// ---------------------------------------------------------------------------
// Fused GEMM0+GEMM1, 32 rows per block (grid = 313 blocks).
// ---------------------------------------------------------------------------
__global__ __launch_bounds__(256) void k_gemm01(
    const unsigned short* __restrict__ xb, const unsigned short* __restrict__ Wb0,
    const unsigned short* __restrict__ Wb1,
    const float* __restrict__ aggw, const float* __restrict__ hrs,
    const float* __restrict__ hrw, const float* __restrict__ bc,
    const float* __restrict__ be, const float* __restrict__ alpha_p,
    float* __restrict__ out_ef, unsigned short* __restrict__ ef_b,
    unsigned short* __restrict__ y_b){
  int wv = threadIdx.x >> 6, lane = threadIdx.x & 63;
  int m0 = blockIdx.x*32;        // block's 32 rows
  int n0 = wv*64;                // wave's 64-col tile
  int lr = lane & 15, lk = (lane >> 4) << 3, rb = (lane >> 4) << 2;
  float alpha = *alpha_p;
  const bf16x8 zero8 = {0,0,0,0,0,0,0,0};
  // ---- phase A ----
  {
    f32x4 acc[2][4];
    #pragma unroll
    for(int a = 0; a < 2; ++a)
      #pragma unroll
      for(int b = 0; b < 4; ++b) acc[a][b] = (f32x4){0.f,0.f,0.f,0.f};
    #pragma unroll
    for(int kc = 0; kc < HD; kc += 32){
      bf16x8 af[2], bfr[4];
      #pragma unroll
      for(int mi = 0; mi < 2; ++mi){
        int r = m0 + mi*16 + lr;
        af[mi] = (r < NHEDGE) ? *(const bf16x8*)&xb[(size_t)r*HD + kc + lk] : zero8;
      }
      #pragma unroll
      for(int ni = 0; ni < 4; ++ni){
        int c = n0 + ni*16 + lr;
        bfr[ni] = *(const bf16x8*)&Wb0[(size_t)c*HD + kc + lk];
      }
      #pragma unroll
      for(int mi = 0; mi < 2; ++mi)
        #pragma unroll
        for(int ni = 0; ni < 4; ++ni)
          acc[mi][ni] = __builtin_amdgcn_mfma_f32_16x16x32_bf16(af[mi], bfr[ni], acc[mi][ni], 0, 0, 0);
    }
    #pragma unroll
    for(int mi = 0; mi < 2; ++mi){
      #pragma unroll
      for(int jj = 0; jj < 4; ++jj){
        int r = m0 + mi*16 + rb + jj;
        if(r < NHEDGE){
          float ra = aggw[r];
          float inv = 1.f / hrs[r];
          #pragma unroll
          for(int ni = 0; ni < 4; ++ni){
            int c = n0 + ni*16 + lr;
            float v = (acc[mi][ni][jj] + ra*bc[c]) * inv;
            v = prelu(v, alpha);
            out_ef[(size_t)r*HD + c] = v;
            ef_b[(size_t)r*HD + c] = f2bf(v);
          }
        }
      }
    }
  }
  __syncthreads();   // block's ef_b rows visible (stores drained to L2)
  // ---- phase B ----
  {
    f32x4 acc[2][4];
    #pragma unroll
    for(int a = 0; a < 2; ++a)
      #pragma unroll
      for(int b = 0; b < 4; ++b) acc[a][b] = (f32x4){0.f,0.f,0.f,0.f};
    #pragma unroll
    for(int kc = 0; kc < HD; kc += 32){
      bf16x8 af[2], bfr[4];
      #pragma unroll
      for(int mi = 0; mi < 2; ++mi){
        int r = m0 + mi*16 + lr;
        af[mi] = (r < NHEDGE) ? *(const bf16x8*)&ef_b[(size_t)r*HD + kc + lk] : zero8;
      }
      #pragma unroll
      for(int ni = 0; ni < 4; ++ni){
        int c = n0 + ni*16 + lr;
        bfr[ni] = *(const bf16x8*)&Wb1[(size_t)c*HD + kc + lk];
      }
      #pragma unroll
      for(int mi = 0; mi < 2; ++mi)
        #pragma unroll
        for(int ni = 0; ni < 4; ++ni)
          acc[mi][ni] = __builtin_amdgcn_mfma_f32_16x16x32_bf16(af[mi], bfr[ni], acc[mi][ni], 0, 0, 0);
    }
    #pragma unroll
    for(int mi = 0; mi < 2; ++mi){
      #pragma unroll
      for(int jj = 0; jj < 4; ++jj){
        int r = m0 + mi*16 + rb + jj;
        if(r < NHEDGE){
          float ra = hrw[r];
          #pragma unroll
          for(int ni = 0; ni < 4; ++ni){
            int c = n0 + ni*16 + lr;
            float v = ra * (acc[mi][ni][jj] + be[c]);
            y_b[(size_t)r*HD + c] = f2bf(v);
          }
        }
      }
    }
  }
}

// ---------------------------------------------------------------------------
// Phase-2 aggregation: 2 nodes per wave, 16B/lane, depth-4 prefetch + epilogue.
// ---------------------------------------------------------------------------
__global__ __launch_bounds__(256) void k_agg2(const unsigned short* __restrict__ yb,
        const int* __restrict__ offs, const int* __restrict__ csrc,
        const float* __restrict__ nrs, const float* __restrict__ alpha_p,
        float* __restrict__ out_nodes){
  int wv = threadIdx.x >> 6, lane = threadIdx.x & 63;
  int sub = lane >> 5, sl = lane & 31;
  int i = blockIdx.x*8 + wv*2 + sub;
  int b = offs[NHEDGE + i], cnt = offs[NHEDGE + i + 1] - b;
  const u16x8* tab = (const u16x8*)yb;
  float acc[8] = {0.f,0.f,0.f,0.f,0.f,0.f,0.f,0.f};
  u16x8 z8 = {0,0,0,0,0,0,0,0};
  u16x8 v0=z8, v1=z8, v2=z8, v3=z8;
  if(cnt > 0){ int j = csrc[b];   v0 = tab[(size_t)j*32 + sl]; }
  if(cnt > 1){ int j = csrc[b+1]; v1 = tab[(size_t)j*32 + sl]; }
  if(cnt > 2){ int j = csrc[b+2]; v2 = tab[(size_t)j*32 + sl]; }
  if(cnt > 3){ int j = csrc[b+3]; v3 = tab[(size_t)j*32 + sl]; }
  int k = 0;
  while(k < cnt){
    { u16x8 cv = v0;
      if(k + 4 < cnt){ int j = csrc[b+k+4]; v0 = tab[(size_t)j*32 + sl]; }
      #pragma unroll
      for(int c = 0; c < 8; ++c) acc[c] += bf2f(cv[c]); }
    if(++k >= cnt) break;
    { u16x8 cv = v1;
      if(k + 4 < cnt){ int j = csrc[b+k+4]; v1 = tab[(size_t)j*32 + sl]; }
      #pragma unroll
      for(int c = 0; c < 8; ++c) acc[c] += bf2f(cv[c]); }
    if(++k >= cnt) break;
    { u16x8 cv = v2;
      if(k + 4 < cnt){ int j = csrc[b+k+4]; v2 = tab[(size_t)j*32 + sl]; }
      #pragma unroll
      for(int c = 0; c < 8; ++c) acc[c] += bf2f(cv[c]); }
    if(++k >= cnt) break;
    { u16x8 cv = v3;
      if(k + 4 < cnt){ int j = csrc[b+k+4]; v3 = tab[(size_t)j*32 + sl]; }
      #pragma unroll
      for(int c = 0; c < 8; ++c) acc[c] += bf2f(cv[c]); }
    ++k;
  }
  float inv = 1.f / nrs[i];
  float a = *alpha_p;
  float4 o1, o2;
  o1.x = prelu(acc[0]*inv, a); o1.y = prelu(acc[1]*inv, a);
  o1.z = prelu(acc[2]*inv, a); o1.w = prelu(acc[3]*inv, a);
  o2.x = prelu(acc[4]*inv, a); o2.y = prelu(acc[5]*inv, a);
  o2.z = prelu(acc[6]*inv, a); o2.w = prelu(acc[7]*inv, a);
  *(float4*)&out_nodes[(size_t)i*HD + sl*8]     = o1;
  *(float4*)&out_nodes[(size_t)i*HD + sl*8 + 4] = o2;
}

// ---------------------------------------------------------------------------
extern "C" void kernel_launch(void* const* d_in, const int* in_sizes, int n_in,
                              void* d_out, int out_size, void* d_ws, size_t ws_size,
                              hipStream_t stream){
  const float* n_feat   = (const float*)d_in[0];
  const int*   node_idx  = (const int*)d_in[2];
  const int*   hedge_idx = (const int*)d_in[3];
  const float* nrw  = (const float*)d_in[4];
  const float* nrs  = (const float*)d_in[5];
  const float* hrw  = (const float*)d_in[6];
  const float* hrs  = (const float*)d_in[7];
  const float* W_in  = (const float*)d_in[8];
  const float* b_in  = (const float*)d_in[9];
  const float* W_n2e = (const float*)d_in[10];
  const float* b_n2e = (const float*)d_in[11];
  const float* W_e2n = (const float*)d_in[12];
  const float* b_e2n = (const float*)d_in[13];
  const float* alpha = (const float*)d_in[14];

  float* out_nodes = (float*)d_out;
  float* out_efeat = out_nodes + (size_t)NNODE * HD;

  // bf16 pre-scaled n_feat table lives in the out_nodes region of d_out: it is
  // consumed only by k_agg1, and k_agg2 (the last kernel) fully overwrites it.
  unsigned short* tabw = (unsigned short*)out_nodes;

  char* p = (char*)d_ws;
  auto take = [&](size_t bytes) -> void* {
    void* r = (void*)p;
    p += (bytes + 255) & ~(size_t)255;
    return r;
  };
  unsigned short* Wb0     = (unsigned short*)take((size_t)HD*HD*2);
  unsigned short* Wb1     = (unsigned short*)take((size_t)HD*HD*2);
  float*          bc      = (float*)take(HD*4);
  float*          aggw    = (float*)take(NHEDGE*4);
  unsigned short* aggx_b  = (unsigned short*)take((size_t)NHEDGE*HD*2);  // aliased as ybuf_b
  unsigned short* efeat_b = (unsigned short*)take((size_t)NHEDGE*HD*2);
  int*            offs    = (int*)take((NS+1)*4);
  int*            cnts    = (int*)take((size_t)NS*PAD*4);   // padded: 1 ctr / 128B
  int*            pos     = (int*)take((size_t)NS*PAD*4);   // padded
  int*            bsum    = (int*)take(SCAN_B*4);
  int*            csrc    = (int*)take((size_t)2*NEDGE*4);
  unsigned short* ybuf_b  = aggx_b;  // safe alias: see k_gemm01 header comment

  k_wprep<<<HD, 256, 0, stream>>>(W_in, b_in, W_n2e, b_n2e, W_e2n, Wb0, Wb1, bc, cnts, pos);
  k_cvt<<<((NNODE*HD)/32 + 255)/256, 256, 0, stream>>>(n_feat, nrw, tabw);
  k_hist<<<HIST_B, 256, 0, stream>>>(node_idx, hedge_idx, cnts);
  k_scanA<<<SCAN_B, 256, 0, stream>>>(cnts, bsum);
  k_scanC<<<SCAN_B, 256, 0, stream>>>(cnts, bsum, offs);
  k_fill<<<HIST_B, 256, 0, stream>>>(node_idx, hedge_idx, offs, pos, csrc);
  k_agg1<<<NHEDGE/8, 256, 0, stream>>>(tabw, nrw, offs, csrc, aggx_b, aggw);
  k_gemm01<<<(NHEDGE + 31)/32, 256, 0, stream>>>(aggx_b, Wb0, Wb1, aggw, hrs, hrw,
                                                 bc, b_e2n, alpha,
                                                 out_efeat, efeat_b, ybuf_b);
  k_agg2<<<NNODE/8, 256, 0, stream>>>(ybuf_b, offs, csrc, nrs, alpha, out_nodes);
}